// Round 5
// baseline (369.634 us; speedup 1.0000x reference)
//
#include <hip/hip_runtime.h>
#include <hip/hip_bf16.h>

// AgentEncoder: B=256, A=512, T=21, DIM=128, SC=6, NHEAD=4, HD=32
// Round 5: round-4 fused structure, with:
//  - __launch_bounds__(256, 8) => VGPR <= 64 (round-4's stage2 fusion pushed the
//    shared frame to 76 VGPR, occupancy 41.5->32%; stage2 spills are fine, it's
//    256/8448 blocks).
//  - stage1 barriers 5 -> 3: s_valid via direct per-agent mask OR (no init
//    phase, no atomics); conv3 epilogue fused into conv3 registers (mean of
//    relu over p accumulated in-reg, stored straight to global with valid mask
//    + type_emb; c3 LDS round-trip and 5th barrier deleted; f32-accurate mean).

#define BB 256
#define AAG 512
#define TT 21
#define NAG (BB * AAG)

typedef __hip_bfloat16 bf16;
typedef __attribute__((ext_vector_type(8))) short s8v;   // 8 bf16 = 4 VGPR
typedef __attribute__((ext_vector_type(4))) float f4v;   // mfma acc

__device__ int g_dtype;        // 1 = bf16 inputs, 0 = f32 inputs
__device__ int g_mask_mode;    // 0=i32, 1=u8, 2=f32, 3=bf16
__device__ __align__(16) short g_w1p[32 * 64];    // [oc][k=tap*16+ic], pad0
__device__ __align__(16) short g_w2p[64 * 96];    // [oc][k=tap*32+ic]
__device__ __align__(16) short g_w3p[128 * 192];  // [oc][k=tap*64+ic]
__device__ __align__(16) float g_b1[32];
__device__ __align__(16) float g_b2[64];
__device__ __align__(16) float g_b3[128];
__device__ __align__(16) float g_wqk[4 * 128];    // per-head q-folded Wk
__device__ __align__(16) float g_qb[4];           // per-head q.bk

template <int DT>
__device__ __forceinline__ float ldf(const void* p, long i) {
    if (DT) return __bfloat162float(((const bf16*)p)[i]);
    return ((const float*)p)[i];
}
template <int DT>
__device__ __forceinline__ void stf(void* p, long i, float v) {
    if (DT) ((bf16*)p)[i] = __float2bfloat16(v);
    else    ((float*)p)[i] = v;
}
__device__ __forceinline__ unsigned short f2bu(float x) {
    bf16 b = __float2bfloat16(x);
    union { bf16 b; unsigned short u; } cv; cv.b = b; return cv.u;
}
__device__ __forceinline__ float bu2f(unsigned short u) {
    union { unsigned int i; float f; } cv; cv.i = ((unsigned int)u) << 16; return cv.f;
}
template <int DT>
__device__ __forceinline__ float2 ldf2(const void* p, long i) {  // i even
    if (DT) {
        unsigned int u = *(const unsigned int*)((const bf16*)p + i);
        return make_float2(bu2f((unsigned short)(u & 0xffffu)),
                           bu2f((unsigned short)(u >> 16)));
    }
    return *(const float2*)((const float*)p + i);
}
__device__ __forceinline__ bool mask_at(const void* p, long i, int mode) {
    if (mode == 0) return ((const int*)p)[i] != 0;
    if (mode == 1) return ((const unsigned char*)p)[i] != 0;
    if (mode == 2) return ((const float*)p)[i] != 0.f;
    return (((const unsigned short*)p)[i] & 0x7fff) != 0;
}

// 64-element row-dot: sum_i W[off+i] * y[i], vectorized 16B loads
template <int DT>
__device__ __forceinline__ float rowdot64(const void* W, long off, const float* y) {
    float acc = 0.f;
    if (DT) {
        const unsigned short* wr = (const unsigned short*)W + off;
#pragma unroll
        for (int i = 0; i < 8; i++) {
            uint4 w = *(const uint4*)(wr + i * 8);
            acc = fmaf(bu2f((unsigned short)(w.x & 0xffffu)), y[i * 8 + 0], acc);
            acc = fmaf(bu2f((unsigned short)(w.x >> 16)),     y[i * 8 + 1], acc);
            acc = fmaf(bu2f((unsigned short)(w.y & 0xffffu)), y[i * 8 + 2], acc);
            acc = fmaf(bu2f((unsigned short)(w.y >> 16)),     y[i * 8 + 3], acc);
            acc = fmaf(bu2f((unsigned short)(w.z & 0xffffu)), y[i * 8 + 4], acc);
            acc = fmaf(bu2f((unsigned short)(w.z >> 16)),     y[i * 8 + 5], acc);
            acc = fmaf(bu2f((unsigned short)(w.w & 0xffffu)), y[i * 8 + 6], acc);
            acc = fmaf(bu2f((unsigned short)(w.w >> 16)),     y[i * 8 + 7], acc);
        }
    } else {
        const float* wr = (const float*)W + off;
#pragma unroll
        for (int i = 0; i < 16; i++) {
            float4 w = *(const float4*)(wr + i * 4);
            acc = fmaf(w.x, y[i * 4 + 0], acc);
            acc = fmaf(w.y, y[i * 4 + 1], acc);
            acc = fmaf(w.z, y[i * 4 + 2], acc);
            acc = fmaf(w.w, y[i * 4 + 3], acc);
        }
    }
    return acc;
}

// ---------------- weight pad/transpose/cast (grid-stride over 64 blocks) ----------------
template <int DT>
__device__ __forceinline__ void prep_body(const void* w1, const void* b1,
                                          const void* w2, const void* b2,
                                          const void* w3, const void* b3) {
    int tid = blockIdx.x * 256 + threadIdx.x;
    const int nt = 64 * 256;
    for (int i = tid; i < 32 * 64; i += nt) {
        int oc = i >> 6, k = i & 63, tap = k >> 4, ic = k & 15;
        float v = (tap < 3 && ic < 9) ? ldf<DT>(w1, oc * 27 + ic * 3 + tap) : 0.f;
        g_w1p[i] = (short)f2bu(v);
    }
    for (int i = tid; i < 64 * 96; i += nt) {
        int oc = i / 96, k = i % 96, tap = k >> 5, ic = k & 31;
        g_w2p[i] = (short)f2bu(ldf<DT>(w2, oc * 96 + ic * 3 + tap));
    }
    for (int i = tid; i < 128 * 192; i += nt) {
        int oc = i / 192, k = i % 192, tap = k >> 6, ic = k & 63;
        g_w3p[i] = (short)f2bu(ldf<DT>(w3, oc * 192 + ic * 3 + tap));
    }
    for (int i = tid; i < 32; i += nt) g_b1[i] = ldf<DT>(b1, i);
    for (int i = tid; i < 64; i += nt) g_b2[i] = ldf<DT>(b2, i);
    for (int i = tid; i < 128; i += nt) g_b3[i] = ldf<DT>(b3, i);
}

// block 64: q = query@Wq^T+bq, then fold through Wk: g_wqk[h][e], g_qb[h]
template <int DT>
__device__ __forceinline__ void qprep_body(const void* query, const void* ipw,
                                           const void* ipb, float* sq) {
    int tid = threadIdx.x;
    if (tid < 128) {
        float acc = ldf<DT>(ipb, tid);
        for (int e = 0; e < 128; e++)
            acc = fmaf(ldf<DT>(query, e), ldf<DT>(ipw, (long)tid * 128 + e), acc);
        sq[tid] = acc;
    }
    __syncthreads();
    int e = tid & 127, hb = tid >> 7;
    for (int h = hb; h < 4; h += 2) {
        float acc = 0.f;
#pragma unroll
        for (int j = 0; j < 32; j++)
            acc = fmaf(sq[h * 32 + j], ldf<DT>(ipw, (long)(128 + h * 32 + j) * 128 + e), acc);
        g_wqk[h * 128 + e] = acc;
    }
    if (tid < 4) {
        float acc = 0.f;
#pragma unroll
        for (int j = 0; j < 32; j++)
            acc = fmaf(sq[tid * 32 + j], ldf<DT>(ipb, 128 + tid * 32 + j), acc);
        g_qb[tid] = acc;
    }
}

// ---------------- launch A: per-block detect + prep + q-fold ----------------
__global__ __launch_bounds__(256) void prep_kernel(
    const unsigned int* __restrict__ pw, const unsigned char* __restrict__ m,
    const void* __restrict__ w1, const void* __restrict__ b1,
    const void* __restrict__ w2, const void* __restrict__ b2,
    const void* __restrict__ w3, const void* __restrict__ b3,
    const void* __restrict__ query, const void* __restrict__ ipw,
    const void* __restrict__ ipb) {
    __shared__ int cls[4];
    __shared__ int mv;
    __shared__ int good;
    __shared__ float sq[128];
    int tid = threadIdx.x;
    if (tid < 4) cls[tid] = 0;
    if (tid == 0) { mv = 0; good = 0; }
    __syncthreads();
    int g = 0;
    for (int i = tid; i < 1024; i += 256) {
        unsigned int w = pw[i];
        unsigned int h0 = w & 0xffffu, h1 = w >> 16;
        unsigned int e0 = (h0 >> 7) & 0xff, e1 = (h1 >> 7) & 0xff;
        if (h0 == 0 || (e0 >= 90 && e0 <= 160)) g++;
        if (h1 == 0 || (e1 >= 90 && e1 <= 160)) g++;
    }
    atomicAdd(&good, g);
    int l0 = 0, l1 = 0, l2 = 0, l3 = 0, lm = 0;
    for (int i = tid; i < 4096; i += 256) {
        int v = m[i];
        if (v) {
            switch (i & 3) { case 0: l0 = 1; break; case 1: l1 = 1; break;
                             case 2: l2 = 1; break; default: l3 = 1; }
            if (v > lm) lm = v;
        }
    }
    if (l0) atomicOr(&cls[0], 1);
    if (l1) atomicOr(&cls[1], 1);
    if (l2) atomicOr(&cls[2], 1);
    if (l3) atomicOr(&cls[3], 1);
    atomicMax(&mv, lm);
    __syncthreads();
    int dt = (good >= 1740) ? 1 : 0;
    int mode;
    if (!cls[1] && !cls[2] && !cls[3]) mode = 0;
    else if (!cls[0] && !cls[1])       mode = 2;
    else if (mv <= 1)                  mode = 1;
    else                               mode = 3;
    if (blockIdx.x == 0 && tid == 0) { g_dtype = dt; g_mask_mode = mode; }

    if (blockIdx.x < 64) {
        if (dt) prep_body<1>(w1, b1, w2, b2, w3, b3);
        else    prep_body<0>(w1, b1, w2, b2, w3, b3);
    } else {
        if (dt) qprep_body<1>(query, ipw, ipb, sq);
        else    qprep_body<0>(query, ipw, ipb, sq);
    }
}

// ---------------- stage 1: 16 agents/block, 4 waves, 3 barriers ----------------
// LDS (shorts). Region A: feat [16][FEAT_AS], reused as h2. Region B: h1
// [16][H1_AS]. Agent strides == +-4 banks (mod 32): lanes step the AGENT axis
// (ag = col) => 2-way bank aliasing (free, m136).
#define FEAT_RS 24     // rows t=0..21 (20/21 zero); 48 B
#define FEAT_AS 568    // 1136 B == -4 banks (mod 32)
#define H1_RS 40       // rows t=0..10 (10 zero); 80 B
#define H1_AS 440      // 880 B == -4 banks
#define H2_RS 72       // rows r=0..6 (0,6 zero); 144 B
#define H2_AS 504      // 1008 B == -4 banks
#define OFF_H1 9088    // shorts = 16*FEAT_AS
#define OFF_VALID 32256 // bytes = 18176 + 16*H1_AS*2
#define SMEM_BYTES 32320 // -> 32768 alloc => 5 blocks/CU

#define MFMA16(a, b, c) __builtin_amdgcn_mfma_f32_16x16x32_bf16((a), (b), (c), 0, 0, 0)

template <int DT>
__device__ __forceinline__ void stage1_body(
    const void* pos, const void* heading, const void* vel, const void* shp,
    const void* vmask, const int* category, const void* type_emb, void* out,
    char* smem, long agent0) {
    short* feat = (short*)smem;               // region A
    short* h1   = (short*)smem + OFF_H1;      // region B
    short* h2   = (short*)smem;               // region A reuse (feat dead after conv1)
    int* s_valid = (int*)(smem + OFF_VALID);

    const int tid = threadIdx.x;
    const int wave = tid >> 6, lane = tid & 63;
    const int col = lane & 15, quad = lane >> 4;
    const int mode = g_mask_mode;

    // ---- phase 1: feature build + h1 zero row + per-agent valid (no atomics) ----
    {
        unsigned int* h1u = (unsigned int*)h1;          // h1 row 10 zero
        h1u[(tid >> 4) * 220 + 200 + (tid & 15)] = 0;
    }
    for (int idx = tid; idx < 16 * 22; idx += 256) {
        int ag = idx / 22, t = idx % 22;
        short* row = feat + ag * FEAT_AS + t * FEAT_RS;
        if (t == 0) {                       // direct OR over the agent's 21 masks
            long b0 = (agent0 + ag) * TT;
            int v = 0;
#pragma unroll
            for (int tt = 0; tt < TT; tt++)
                v |= mask_at(vmask, b0 + tt, mode) ? 1 : 0;
            s_valid[ag] = v;
        }
        if (t >= 20) {
            *(uint4*)row = make_uint4(0, 0, 0, 0);
            *(uint4*)(row + 8) = make_uint4(0, 0, 0, 0);
        } else {
            long base = (agent0 + ag) * TT + t;
            bool vmt = mask_at(vmask, base, mode);
            bool m2 = vmt && mask_at(vmask, base + 1, mode);
            float2 pa = ldf2<DT>(pos, base * 2), pb = ldf2<DT>(pos, base * 2 + 2);
            float2 va = ldf2<DT>(vel, base * 2), vb = ldf2<DT>(vel, base * 2 + 2);
            float hh0 = ldf<DT>(heading, base), hh1 = ldf<DT>(heading, base + 1);
            float2 sv = ldf2<DT>(shp, base * 2 + 2);
            float dh = m2 ? (hh1 - hh0) : 0.f;      // masked: cos=1, sin=0 (ref)
            float sn, cn;
            __sincosf(dh, &sn, &cn);
            unsigned int p0 = f2bu(m2 ? pb.x - pa.x : 0.f) | ((unsigned int)f2bu(m2 ? pb.y - pa.y : 0.f) << 16);
            unsigned int p1 = f2bu(m2 ? vb.x - va.x : 0.f) | ((unsigned int)f2bu(m2 ? vb.y - va.y : 0.f) << 16);
            unsigned int p2 = f2bu(cn) | ((unsigned int)f2bu(sn) << 16);
            unsigned int p3 = f2bu(sv.x) | ((unsigned int)f2bu(sv.y) << 16);
            unsigned int p4 = (unsigned int)f2bu(m2 ? 1.f : 0.f);
            *(uint4*)row = make_uint4(p0, p1, p2, p3);
            *(uint4*)(row + 8) = make_uint4(p4, 0, 0, 0);
        }
    }
    __syncthreads();

    // ---- conv1: M=32 (2 Mt), K=64, N=16ag x 10p => ag=col, p per-iter ----
    {
        int Mt = wave >> 1;
        int oc = Mt * 16 + col;
        s8v a0 = *(const s8v*)(g_w1p + oc * 64 + quad * 8);
        s8v a1 = *(const s8v*)(g_w1p + oc * 64 + 32 + quad * 8);
        int k0 = quad * 8, k1 = 32 + quad * 8;
        int tap0 = k0 >> 4, ic0 = k0 & 15;
        int tap1 = k1 >> 4, ic1 = k1 & 15;
        int ocr = Mt * 16 + quad * 4;
        f4v bia = *(const f4v*)(g_b1 + ocr);
        int ag = col;
        const short* agbase = feat + ag * FEAT_AS;
#pragma unroll
        for (int i = 0; i < 5; i++) {
            int p = (wave & 1) * 5 + i;
            const short* bb = agbase + 2 * p * FEAT_RS;
            s8v b0 = *(const s8v*)(bb + tap0 * FEAT_RS + ic0);
            s8v b1 = *(const s8v*)(bb + tap1 * FEAT_RS + ic1);
            f4v acc = {0.f, 0.f, 0.f, 0.f};
            acc = MFMA16(a0, b0, acc);
            acc = MFMA16(a1, b1, acc);
            unsigned int lo = f2bu(fmaxf(acc[0] + bia[0], 0.f)) | ((unsigned int)f2bu(fmaxf(acc[1] + bia[1], 0.f)) << 16);
            unsigned int hi = f2bu(fmaxf(acc[2] + bia[2], 0.f)) | ((unsigned int)f2bu(fmaxf(acc[3] + bia[3], 0.f)) << 16);
            *(uint2*)(h1 + ag * H1_AS + p * H1_RS + ocr) = make_uint2(lo, hi);
        }
    }
    __syncthreads();

    // ---- conv2: M=64 (4 Mt), K=96, N=16ag x 5p => ag=col, p=Nt. Zero h2 pad
    //      rows 0 & 6 first (region A: feat dead) ----
    {
        unsigned int* h2u = (unsigned int*)h2;
        for (int i = tid; i < 1024; i += 256) {
            int a2 = i >> 6, r = (i >> 5) & 1, cc = i & 31;
            h2u[a2 * 252 + r * 216 + cc] = 0;
        }
        int Mt = wave;
        int oc = Mt * 16 + col;
        s8v a[3];
#pragma unroll
        for (int ks = 0; ks < 3; ks++)
            a[ks] = *(const s8v*)(g_w2p + oc * 96 + ks * 32 + quad * 8);
        int ocr = Mt * 16 + quad * 4;
        f4v bia = *(const f4v*)(g_b2 + ocr);
        int ag = col;
#pragma unroll
        for (int p = 0; p < 5; p++) {
            f4v acc = {0.f, 0.f, 0.f, 0.f};
#pragma unroll
            for (int ks = 0; ks < 3; ks++) {
                s8v b = *(const s8v*)(h1 + ag * H1_AS + (2 * p + ks) * H1_RS + quad * 8);
                acc = MFMA16(a[ks], b, acc);
            }
            unsigned int lo = f2bu(fmaxf(acc[0] + bia[0], 0.f)) | ((unsigned int)f2bu(fmaxf(acc[1] + bia[1], 0.f)) << 16);
            unsigned int hi = f2bu(fmaxf(acc[2] + bia[2], 0.f)) | ((unsigned int)f2bu(fmaxf(acc[3] + bia[3], 0.f)) << 16);
            *(uint2*)(h2 + ag * H2_AS + (p + 1) * H2_RS + ocr) = make_uint2(lo, hi);
        }
    }
    __syncthreads();

    // ---- conv3 + fused epilogue: M=128 (8 Mt, 2/wave), K=192, mean over p in
    //      registers, direct global store (valid mask + type_emb) ----
    {
        int ag = col;
        long agl = agent0 + ag;
        bool skip = ((agl & (AAG - 1)) == 0);   // stage2 owns out[b][0]
        int valid = s_valid[ag];
        int cat = category[agl];
#pragma unroll
        for (int m2 = 0; m2 < 2; m2++) {
            int Mt = wave * 2 + m2;
            int oc = Mt * 16 + col;
            s8v a[6];
#pragma unroll
            for (int ks = 0; ks < 6; ks++)
                a[ks] = *(const s8v*)(g_w3p + oc * 192 + ks * 32 + quad * 8);
            int ocr = Mt * 16 + quad * 4;
            f4v bia = *(const f4v*)(g_b3 + ocr);
            f4v macc = {0.f, 0.f, 0.f, 0.f};
#pragma unroll
            for (int p = 0; p < 3; p++) {
                f4v acc = {0.f, 0.f, 0.f, 0.f};
#pragma unroll
                for (int ks = 0; ks < 6; ks++) {
                    int kg = ks * 32 + quad * 8;
                    int tap = kg >> 6, ic = kg & 63;
                    s8v b = *(const s8v*)(h2 + ag * H2_AS + (2 * p + tap) * H2_RS + ic);
                    acc = MFMA16(a[ks], b, acc);
                }
#pragma unroll
                for (int j = 0; j < 4; j++)
                    macc[j] += fmaxf(acc[j] + bia[j], 0.f);
            }
            if (!skip) {
                float vals[4];
#pragma unroll
                for (int j = 0; j < 4; j++)
                    vals[j] = valid ? macc[j] * (1.f / 3.f) : 0.f;
                if (DT) {
                    const unsigned short* tep = (const unsigned short*)type_emb + (long)cat * 128 + ocr;
                    uint2 te = *(const uint2*)tep;
                    unsigned int lo = f2bu(vals[0] + bu2f((unsigned short)(te.x & 0xffffu))) |
                                      ((unsigned int)f2bu(vals[1] + bu2f((unsigned short)(te.x >> 16))) << 16);
                    unsigned int hi = f2bu(vals[2] + bu2f((unsigned short)(te.y & 0xffffu))) |
                                      ((unsigned int)f2bu(vals[3] + bu2f((unsigned short)(te.y >> 16))) << 16);
                    *(uint2*)((bf16*)out + agl * 128 + ocr) = make_uint2(lo, hi);
                } else {
                    float4 te = *(const float4*)((const float*)type_emb + (long)cat * 128 + ocr);
                    float4 o = make_float4(vals[0] + te.x, vals[1] + te.y,
                                           vals[2] + te.z, vals[3] + te.w);
                    *(float4*)((float*)out + agl * 128 + ocr) = o;
                }
            }
        }
    }
}

// ---------------- stage 2 (256 threads): ego cross-attention, writes out[b][0] ----------------
// q/k pre-folded (g_wqk, g_qb). softmax weights sum to 1 =>
// o[d] = bv[d] + sum_e y_{h(d)}[e] * Wv[d][e], y_h[e] = sum_s att[h,s]*xe[s,e].
template <int DT>
__device__ __forceinline__ void stage2_body(
    const void* cs, const int* category,
    const void* se_w, const void* se_b, const void* pe,
    const void* ipw, const void* ipb, const void* opw, const void* opb,
    const void* type_emb, void* out, char* smem) {
    const int b = blockIdx.x;
    const int tid = threadIdx.x;
    const int d = tid & 127, half = tid >> 7;

    float* s_xe  = (float*)smem;        // [6][128]
    float* s_y   = s_xe + 768;          // [4][128]
    float* s_sc  = s_y + 512;           // [4*6] (+pad)
    float* s_att = s_sc + 32;           // [4*6] (+pad)
    float* s_o   = s_att + 32;          // [128]
    float* s_par = s_o + 128;           // [2][128]

    for (int idx = tid; idx < 768; idx += 256) {
        int s = idx >> 7, dd = idx & 127;
        float ego = ldf<DT>(cs, b * 6 + s);
        s_xe[idx] = fmaf(ego, ldf<DT>(se_w, s * 128 + dd),
                         ldf<DT>(se_b, s * 128 + dd) + ldf<DT>(pe, s * 128 + dd));
    }
    __syncthreads();

    // scores: 24 (h,s) pairs x 4 lanes each, 32-e partials + width-4 reduce
    if (tid < 96) {
        int g = tid >> 2, lig = tid & 3;
        int h = g / 6, s = g - h * 6;
        const float* xr = s_xe + s * 128 + lig * 32;
        const float* wr = g_wqk + h * 128 + lig * 32;
        float t = 0.f;
#pragma unroll
        for (int e = 0; e < 32; e++) t = fmaf(xr[e], wr[e], t);
        t += __shfl_xor(t, 1, 4);
        t += __shfl_xor(t, 2, 4);
        if (lig == 0) s_sc[g] = (t + g_qb[h]) * 0.17677669529663687f;
    }
    __syncthreads();

    if (tid < 4) {
        float mx = -1e30f;
#pragma unroll
        for (int s = 0; s < 6; s++) mx = fmaxf(mx, s_sc[tid * 6 + s]);
        float sum = 0.f, ex[6];
#pragma unroll
        for (int s = 0; s < 6; s++) { ex[s] = expf(s_sc[tid * 6 + s] - mx); sum += ex[s]; }
        float inv = 1.f / sum;
#pragma unroll
        for (int s = 0; s < 6; s++) s_att[tid * 6 + s] = ex[s] * inv;
    }
    __syncthreads();

    for (int idx = tid; idx < 512; idx += 256) {
        int h = idx >> 7, e = idx & 127;
        float y = 0.f;
#pragma unroll
        for (int s = 0; s < 6; s++) y = fmaf(s_att[h * 6 + s], s_xe[s * 128 + e], y);
        s_y[idx] = y;
    }
    __syncthreads();

    {   // o[d] partial over 64 e (Wv row = ipw row 256+d)
        int h = d >> 5;
        const float* yr = s_y + h * 128 + half * 64;
        s_par[half * 128 + d] = rowdot64<DT>(ipw, (long)(256 + d) * 128 + half * 64, yr);
    }
    __syncthreads();
    if (half == 0) s_o[d] = s_par[d] + s_par[128 + d] + ldf<DT>(ipb, 256 + d);
    __syncthreads();

    {   // x_ego[d] partial over 64 e (Wo row d)
        const float* orr = s_o + half * 64;
        s_par[half * 128 + d] = rowdot64<DT>(opw, (long)d * 128 + half * 64, orr);
    }
    __syncthreads();
    if (half == 0) {
        float x = s_par[d] + s_par[128 + d] + ldf<DT>(opb, d);
        int cat = category[(long)b * AAG];
        stf<DT>(out, (long)b * AAG * 128 + d, x + ldf<DT>(type_emb, cat * 128 + d));
    }
}

// ---------------- launch B: fused stage2 (blocks<256) + stage1 ----------------
__global__ __launch_bounds__(256, 8) void fused_kernel(
    const void* __restrict__ pos, const void* __restrict__ heading,
    const void* __restrict__ vel, const void* __restrict__ shp,
    const void* __restrict__ vmask, const int* __restrict__ category,
    const void* __restrict__ type_emb, void* __restrict__ out,
    const void* __restrict__ cs, const void* __restrict__ se_w,
    const void* __restrict__ se_b, const void* __restrict__ pe,
    const void* __restrict__ ipw, const void* __restrict__ ipb,
    const void* __restrict__ opw, const void* __restrict__ opb) {
    __shared__ __align__(16) char smem[SMEM_BYTES];
    if (blockIdx.x < BB) {
        if (g_dtype) stage2_body<1>(cs, category, se_w, se_b, pe, ipw, ipb, opw, opb, type_emb, out, smem);
        else         stage2_body<0>(cs, category, se_w, se_b, pe, ipw, ipb, opw, opb, type_emb, out, smem);
    } else {
        long agent0 = (long)(blockIdx.x - BB) * 16;
        if (g_dtype) stage1_body<1>(pos, heading, vel, shp, vmask, category, type_emb, out, smem, agent0);
        else         stage1_body<0>(pos, heading, vel, shp, vmask, category, type_emb, out, smem, agent0);
    }
}

extern "C" void kernel_launch(void* const* d_in, const int* in_sizes, int n_in,
                              void* d_out, int out_size, void* d_ws, size_t ws_size,
                              hipStream_t stream) {
    const void* position      = d_in[0];
    const void* heading       = d_in[1];
    const void* velocity      = d_in[2];
    const void* shape         = d_in[3];
    const void* current_state = d_in[4];
    const int*  category      = (const int*)d_in[5];
    const void* valid_mask    = d_in[6];
    const void* conv1_w = d_in[7];
    const void* conv1_b = d_in[8];
    const void* conv2_w = d_in[9];
    const void* conv2_b = d_in[10];
    const void* conv3_w = d_in[11];
    const void* conv3_b = d_in[12];
    const void* se_w    = d_in[13];
    const void* se_b    = d_in[14];
    const void* pos_embed = d_in[15];
    const void* query     = d_in[16];
    const void* in_proj_w = d_in[17];
    const void* in_proj_b = d_in[18];
    const void* out_proj_w = d_in[19];
    const void* out_proj_b = d_in[20];
    const void* type_emb   = d_in[21];

    hipLaunchKernelGGL(prep_kernel, dim3(65), dim3(256), 0, stream,
                       (const unsigned int*)position, (const unsigned char*)valid_mask,
                       conv1_w, conv1_b, conv2_w, conv2_b, conv3_w, conv3_b,
                       query, in_proj_w, in_proj_b);

    hipLaunchKernelGGL(fused_kernel, dim3(BB + NAG / 16), dim3(256), 0, stream,
                       position, heading, velocity, shape, valid_mask, category,
                       type_emb, d_out,
                       current_state, se_w, se_b, pos_embed,
                       in_proj_w, in_proj_b, out_proj_w, out_proj_b);
}

// Round 6
// 331.918 us; speedup vs baseline: 1.1136x; 1.1136x over previous
//
#include <hip/hip_runtime.h>
#include <hip/hip_bf16.h>

// AgentEncoder: B=256, A=512, T=21, DIM=128, SC=6, NHEAD=4, HD=32
// Round 6: round-1 verified stage1 body (131us @ 44 VGPR) with a 12-agent
// block: identical LDS strides (bank behavior preserved), regions scale to
// 24240 B => 6 blocks/CU (24 waves, +20% occupancy). Garbage MFMA cols 12-15
// clamp-read ag=11 and are write-masked. Barriers 5 -> 4 (valid via t0-OR in
// the feature phase). Stage2 back to its own slim dispatch (regalloc isolation;
// round-4/5 lesson: fusion pushes the frame past the 64-VGPR occupancy cliff).
// Round-5 lesson kept: epilogue stays LDS-staged + coalesced row stores.

#define BB 256
#define AAG 512
#define TT 21
#define NAG (BB * AAG)
#define AB 12                 // agents per stage1 block
#define NB1 ((NAG + AB - 1) / AB)

typedef __hip_bfloat16 bf16;
typedef __attribute__((ext_vector_type(8))) short s8v;   // 8 bf16 = 4 VGPR
typedef __attribute__((ext_vector_type(4))) float f4v;   // mfma acc

__device__ int g_dtype;        // 1 = bf16 inputs, 0 = f32 inputs
__device__ int g_mask_mode;    // 0=i32, 1=u8, 2=f32, 3=bf16
__device__ __align__(16) short g_w1p[32 * 64];    // [oc][k=tap*16+ic], pad0
__device__ __align__(16) short g_w2p[64 * 96];    // [oc][k=tap*32+ic]
__device__ __align__(16) short g_w3p[128 * 192];  // [oc][k=tap*64+ic]
__device__ __align__(16) float g_b1[32];
__device__ __align__(16) float g_b2[64];
__device__ __align__(16) float g_b3[128];
__device__ __align__(16) float g_wqk[4 * 128];    // per-head q-folded Wk
__device__ __align__(16) float g_qb[4];           // per-head q.bk

template <int DT>
__device__ __forceinline__ float ldf(const void* p, long i) {
    if (DT) return __bfloat162float(((const bf16*)p)[i]);
    return ((const float*)p)[i];
}
template <int DT>
__device__ __forceinline__ void stf(void* p, long i, float v) {
    if (DT) ((bf16*)p)[i] = __float2bfloat16(v);
    else    ((float*)p)[i] = v;
}
__device__ __forceinline__ unsigned short f2bu(float x) {
    bf16 b = __float2bfloat16(x);
    union { bf16 b; unsigned short u; } cv; cv.b = b; return cv.u;
}
__device__ __forceinline__ float bu2f(unsigned short u) {
    union { unsigned int i; float f; } cv; cv.i = ((unsigned int)u) << 16; return cv.f;
}
template <int DT>
__device__ __forceinline__ float2 ldf2(const void* p, long i) {  // i even
    if (DT) {
        unsigned int u = *(const unsigned int*)((const bf16*)p + i);
        return make_float2(bu2f((unsigned short)(u & 0xffffu)),
                           bu2f((unsigned short)(u >> 16)));
    }
    return *(const float2*)((const float*)p + i);
}
__device__ __forceinline__ bool mask_at(const void* p, long i, int mode) {
    if (mode == 0) return ((const int*)p)[i] != 0;
    if (mode == 1) return ((const unsigned char*)p)[i] != 0;
    if (mode == 2) return ((const float*)p)[i] != 0.f;
    return (((const unsigned short*)p)[i] & 0x7fff) != 0;
}

// 64-element row-dot: sum_i W[off+i] * y[i], vectorized 16B loads
template <int DT>
__device__ __forceinline__ float rowdot64(const void* W, long off, const float* y) {
    float acc = 0.f;
    if (DT) {
        const unsigned short* wr = (const unsigned short*)W + off;
#pragma unroll
        for (int i = 0; i < 8; i++) {
            uint4 w = *(const uint4*)(wr + i * 8);
            acc = fmaf(bu2f((unsigned short)(w.x & 0xffffu)), y[i * 8 + 0], acc);
            acc = fmaf(bu2f((unsigned short)(w.x >> 16)),     y[i * 8 + 1], acc);
            acc = fmaf(bu2f((unsigned short)(w.y & 0xffffu)), y[i * 8 + 2], acc);
            acc = fmaf(bu2f((unsigned short)(w.y >> 16)),     y[i * 8 + 3], acc);
            acc = fmaf(bu2f((unsigned short)(w.z & 0xffffu)), y[i * 8 + 4], acc);
            acc = fmaf(bu2f((unsigned short)(w.z >> 16)),     y[i * 8 + 5], acc);
            acc = fmaf(bu2f((unsigned short)(w.w & 0xffffu)), y[i * 8 + 6], acc);
            acc = fmaf(bu2f((unsigned short)(w.w >> 16)),     y[i * 8 + 7], acc);
        }
    } else {
        const float* wr = (const float*)W + off;
#pragma unroll
        for (int i = 0; i < 16; i++) {
            float4 w = *(const float4*)(wr + i * 4);
            acc = fmaf(w.x, y[i * 4 + 0], acc);
            acc = fmaf(w.y, y[i * 4 + 1], acc);
            acc = fmaf(w.z, y[i * 4 + 2], acc);
            acc = fmaf(w.w, y[i * 4 + 3], acc);
        }
    }
    return acc;
}

// ---------------- weight pad/transpose/cast (grid-stride over 64 blocks) ----------------
template <int DT>
__device__ __forceinline__ void prep_body(const void* w1, const void* b1,
                                          const void* w2, const void* b2,
                                          const void* w3, const void* b3) {
    int tid = blockIdx.x * 256 + threadIdx.x;
    const int nt = 64 * 256;
    for (int i = tid; i < 32 * 64; i += nt) {
        int oc = i >> 6, k = i & 63, tap = k >> 4, ic = k & 15;
        float v = (tap < 3 && ic < 9) ? ldf<DT>(w1, oc * 27 + ic * 3 + tap) : 0.f;
        g_w1p[i] = (short)f2bu(v);
    }
    for (int i = tid; i < 64 * 96; i += nt) {
        int oc = i / 96, k = i % 96, tap = k >> 5, ic = k & 31;
        g_w2p[i] = (short)f2bu(ldf<DT>(w2, oc * 96 + ic * 3 + tap));
    }
    for (int i = tid; i < 128 * 192; i += nt) {
        int oc = i / 192, k = i % 192, tap = k >> 6, ic = k & 63;
        g_w3p[i] = (short)f2bu(ldf<DT>(w3, oc * 192 + ic * 3 + tap));
    }
    for (int i = tid; i < 32; i += nt) g_b1[i] = ldf<DT>(b1, i);
    for (int i = tid; i < 64; i += nt) g_b2[i] = ldf<DT>(b2, i);
    for (int i = tid; i < 128; i += nt) g_b3[i] = ldf<DT>(b3, i);
}

// block 64: q = query@Wq^T+bq, then fold through Wk: g_wqk[h][e], g_qb[h]
template <int DT>
__device__ __forceinline__ void qprep_body(const void* query, const void* ipw,
                                           const void* ipb, float* sq) {
    int tid = threadIdx.x;
    if (tid < 128) {
        float acc = ldf<DT>(ipb, tid);
        for (int e = 0; e < 128; e++)
            acc = fmaf(ldf<DT>(query, e), ldf<DT>(ipw, (long)tid * 128 + e), acc);
        sq[tid] = acc;
    }
    __syncthreads();
    int e = tid & 127, hb = tid >> 7;
    for (int h = hb; h < 4; h += 2) {
        float acc = 0.f;
#pragma unroll
        for (int j = 0; j < 32; j++)
            acc = fmaf(sq[h * 32 + j], ldf<DT>(ipw, (long)(128 + h * 32 + j) * 128 + e), acc);
        g_wqk[h * 128 + e] = acc;
    }
    if (tid < 4) {
        float acc = 0.f;
#pragma unroll
        for (int j = 0; j < 32; j++)
            acc = fmaf(sq[tid * 32 + j], ldf<DT>(ipb, 128 + tid * 32 + j), acc);
        g_qb[tid] = acc;
    }
}

// ---------------- launch A: per-block detect + prep + q-fold ----------------
__global__ __launch_bounds__(256) void prep_kernel(
    const unsigned int* __restrict__ pw, const unsigned char* __restrict__ m,
    const void* __restrict__ w1, const void* __restrict__ b1,
    const void* __restrict__ w2, const void* __restrict__ b2,
    const void* __restrict__ w3, const void* __restrict__ b3,
    const void* __restrict__ query, const void* __restrict__ ipw,
    const void* __restrict__ ipb) {
    __shared__ int cls[4];
    __shared__ int mv;
    __shared__ int good;
    __shared__ float sq[128];
    int tid = threadIdx.x;
    if (tid < 4) cls[tid] = 0;
    if (tid == 0) { mv = 0; good = 0; }
    __syncthreads();
    int g = 0;
    for (int i = tid; i < 1024; i += 256) {
        unsigned int w = pw[i];
        unsigned int h0 = w & 0xffffu, h1 = w >> 16;
        unsigned int e0 = (h0 >> 7) & 0xff, e1 = (h1 >> 7) & 0xff;
        if (h0 == 0 || (e0 >= 90 && e0 <= 160)) g++;
        if (h1 == 0 || (e1 >= 90 && e1 <= 160)) g++;
    }
    atomicAdd(&good, g);
    int l0 = 0, l1 = 0, l2 = 0, l3 = 0, lm = 0;
    for (int i = tid; i < 4096; i += 256) {
        int v = m[i];
        if (v) {
            switch (i & 3) { case 0: l0 = 1; break; case 1: l1 = 1; break;
                             case 2: l2 = 1; break; default: l3 = 1; }
            if (v > lm) lm = v;
        }
    }
    if (l0) atomicOr(&cls[0], 1);
    if (l1) atomicOr(&cls[1], 1);
    if (l2) atomicOr(&cls[2], 1);
    if (l3) atomicOr(&cls[3], 1);
    atomicMax(&mv, lm);
    __syncthreads();
    int dt = (good >= 1740) ? 1 : 0;
    int mode;
    if (!cls[1] && !cls[2] && !cls[3]) mode = 0;
    else if (!cls[0] && !cls[1])       mode = 2;
    else if (mv <= 1)                  mode = 1;
    else                               mode = 3;
    if (blockIdx.x == 0 && tid == 0) { g_dtype = dt; g_mask_mode = mode; }

    if (blockIdx.x < 64) {
        if (dt) prep_body<1>(w1, b1, w2, b2, w3, b3);
        else    prep_body<0>(w1, b1, w2, b2, w3, b3);
    } else {
        if (dt) qprep_body<1>(query, ipw, ipb, sq);
        else    qprep_body<0>(query, ipw, ipb, sq);
    }
}

// ---------------- stage 1: 12 agents/block, 4 waves, 4 barriers ----------------
// LDS (shorts). Region A: feat [12][FEAT_AS], reused as h2. Region B: h1
// [12][H1_AS], reused as c3. All strides identical to the measured round-1
// layout (bank behavior preserved); only region counts shrink 16 -> 12.
// MFMA cols 12-15 are garbage: reads clamp to ag=11, writes masked col<12.
#define FEAT_RS 24     // rows t=0..21 (20/21 zero); 48 B
#define FEAT_AS 568    // 1136 B == -4 banks (mod 32)
#define H1_RS 40       // rows t=0..10 (10 zero); 80 B
#define H1_AS 440      // 880 B == -4 banks
#define H2_RS 72       // rows r=0..6 (0,6 zero); 144 B
#define H2_AS 504      // 1008 B == -4 banks
#define C3_AS 392      // 3*128 + 8 pad; 784 B == +4 banks
#define OFF_H1 6816    // shorts = 12*FEAT_AS
#define OFF_VALID 24192 // bytes = (OFF_H1 + 12*H1_AS)*2
#define SMEM_BYTES 24240 // -> <=24576 alloc => 6 blocks/CU (24 waves)

#define MFMA16(a, b, c) __builtin_amdgcn_mfma_f32_16x16x32_bf16((a), (b), (c), 0, 0, 0)

template <int DT>
__device__ __forceinline__ void stage1_body(
    const void* pos, const void* heading, const void* vel, const void* shp,
    const void* vmask, const int* category, const void* type_emb, void* out,
    char* smem, long agent0) {
    short* feat = (short*)smem;               // region A
    short* h1   = (short*)smem + OFF_H1;      // region B
    short* h2   = (short*)smem;               // region A reuse (feat dead after conv1)
    short* c3   = (short*)smem + OFF_H1;      // region B reuse (h1 dead after conv2)
    int* s_valid = (int*)(smem + OFF_VALID);

    const int tid = threadIdx.x;
    const int wave = tid >> 6, lane = tid & 63;
    const int col = lane & 15, quad = lane >> 4;
    const int cg = col < AB ? col : AB - 1;   // clamped agent for garbage cols
    const int mode = g_mask_mode;

    // ---- phase 1: feature build + h1 zero row + per-agent valid (t0-OR) ----
    if (tid < AB * 16) {                      // h1 row 10 zero (32 shorts/agent)
        unsigned int* h1u = (unsigned int*)h1;
        h1u[(tid >> 4) * 220 + 200 + (tid & 15)] = 0;
    }
    for (int idx = tid; idx < AB * 22; idx += 256) {
        int ag = idx / 22, t = idx % 22;
        long agl = agent0 + ag;
        bool live = agl < NAG;
        short* row = feat + ag * FEAT_AS + t * FEAT_RS;
        if (t == 0) {                         // direct OR over the agent's 21 masks
            int v = 0;
            if (live) {
                long b0 = agl * TT;
#pragma unroll
                for (int tt = 0; tt < TT; tt++)
                    v |= mask_at(vmask, b0 + tt, mode) ? 1 : 0;
            }
            s_valid[ag] = v;
        }
        if (t >= 20 || !live) {
            *(uint4*)row = make_uint4(0, 0, 0, 0);
            *(uint4*)(row + 8) = make_uint4(0, 0, 0, 0);
        } else {
            long base = agl * TT + t;
            bool vmt = mask_at(vmask, base, mode);
            bool m2 = vmt && mask_at(vmask, base + 1, mode);
            float2 pa = ldf2<DT>(pos, base * 2), pb = ldf2<DT>(pos, base * 2 + 2);
            float2 va = ldf2<DT>(vel, base * 2), vb = ldf2<DT>(vel, base * 2 + 2);
            float hh0 = ldf<DT>(heading, base), hh1 = ldf<DT>(heading, base + 1);
            float2 sv = ldf2<DT>(shp, base * 2 + 2);
            float dh = m2 ? (hh1 - hh0) : 0.f;      // masked: cos=1, sin=0 (ref)
            float sn, cn;
            __sincosf(dh, &sn, &cn);
            unsigned int p0 = f2bu(m2 ? pb.x - pa.x : 0.f) | ((unsigned int)f2bu(m2 ? pb.y - pa.y : 0.f) << 16);
            unsigned int p1 = f2bu(m2 ? vb.x - va.x : 0.f) | ((unsigned int)f2bu(m2 ? vb.y - va.y : 0.f) << 16);
            unsigned int p2 = f2bu(cn) | ((unsigned int)f2bu(sn) << 16);
            unsigned int p3 = f2bu(sv.x) | ((unsigned int)f2bu(sv.y) << 16);
            unsigned int p4 = (unsigned int)f2bu(m2 ? 1.f : 0.f);
            *(uint4*)row = make_uint4(p0, p1, p2, p3);
            *(uint4*)(row + 8) = make_uint4(p4, 0, 0, 0);
        }
    }
    __syncthreads();

    // ---- conv1: M=32 (2 Mt), K=64, N=12ag x 10p => ag=col (clamped) ----
    {
        int Mt = wave >> 1;
        int oc = Mt * 16 + col;
        s8v a0 = *(const s8v*)(g_w1p + oc * 64 + quad * 8);
        s8v a1 = *(const s8v*)(g_w1p + oc * 64 + 32 + quad * 8);
        int k0 = quad * 8, k1 = 32 + quad * 8;
        int tap0 = k0 >> 4, ic0 = k0 & 15;
        int tap1 = k1 >> 4, ic1 = k1 & 15;
        int ocr = Mt * 16 + quad * 4;
        f4v bia = *(const f4v*)(g_b1 + ocr);
        const short* agbase = feat + cg * FEAT_AS;
#pragma unroll
        for (int i = 0; i < 5; i++) {
            int p = (wave & 1) * 5 + i;
            const short* bb = agbase + 2 * p * FEAT_RS;
            s8v b0 = *(const s8v*)(bb + tap0 * FEAT_RS + ic0);
            s8v b1 = *(const s8v*)(bb + tap1 * FEAT_RS + ic1);
            f4v acc = {0.f, 0.f, 0.f, 0.f};
            acc = MFMA16(a0, b0, acc);
            acc = MFMA16(a1, b1, acc);
            if (col < AB) {
                unsigned int lo = f2bu(fmaxf(acc[0] + bia[0], 0.f)) | ((unsigned int)f2bu(fmaxf(acc[1] + bia[1], 0.f)) << 16);
                unsigned int hi = f2bu(fmaxf(acc[2] + bia[2], 0.f)) | ((unsigned int)f2bu(fmaxf(acc[3] + bia[3], 0.f)) << 16);
                *(uint2*)(h1 + col * H1_AS + p * H1_RS + ocr) = make_uint2(lo, hi);
            }
        }
    }
    __syncthreads();

    // ---- conv2: M=64 (4 Mt), K=96, N=12ag x 5p. Zero h2 pad rows 0 & 6 first ----
    {
        unsigned int* h2u = (unsigned int*)h2;
        for (int i = tid; i < AB * 64; i += 256) {
            int a2 = i >> 6, r = (i >> 5) & 1, cc = i & 31;
            h2u[a2 * 252 + r * 216 + cc] = 0;
        }
        int Mt = wave;
        int oc = Mt * 16 + col;
        s8v a[3];
#pragma unroll
        for (int ks = 0; ks < 3; ks++)
            a[ks] = *(const s8v*)(g_w2p + oc * 96 + ks * 32 + quad * 8);
        int ocr = Mt * 16 + quad * 4;
        f4v bia = *(const f4v*)(g_b2 + ocr);
#pragma unroll
        for (int p = 0; p < 5; p++) {
            f4v acc = {0.f, 0.f, 0.f, 0.f};
#pragma unroll
            for (int ks = 0; ks < 3; ks++) {
                s8v b = *(const s8v*)(h1 + cg * H1_AS + (2 * p + ks) * H1_RS + quad * 8);
                acc = MFMA16(a[ks], b, acc);
            }
            if (col < AB) {
                unsigned int lo = f2bu(fmaxf(acc[0] + bia[0], 0.f)) | ((unsigned int)f2bu(fmaxf(acc[1] + bia[1], 0.f)) << 16);
                unsigned int hi = f2bu(fmaxf(acc[2] + bia[2], 0.f)) | ((unsigned int)f2bu(fmaxf(acc[3] + bia[3], 0.f)) << 16);
                *(uint2*)(h2 + col * H2_AS + (p + 1) * H2_RS + ocr) = make_uint2(lo, hi);
            }
        }
    }
    __syncthreads();

    // ---- conv3: M=128 (8 Mt, 2/wave), K=192 (6 slices), N=12ag x 3p ----
#pragma unroll
    for (int m2 = 0; m2 < 2; m2++) {
        int Mt = wave * 2 + m2;
        int oc = Mt * 16 + col;
        s8v a[6];
#pragma unroll
        for (int ks = 0; ks < 6; ks++)
            a[ks] = *(const s8v*)(g_w3p + oc * 192 + ks * 32 + quad * 8);
        int ocr = Mt * 16 + quad * 4;
        f4v bia = *(const f4v*)(g_b3 + ocr);
#pragma unroll
        for (int p = 0; p < 3; p++) {
            f4v acc = {0.f, 0.f, 0.f, 0.f};
#pragma unroll
            for (int ks = 0; ks < 6; ks++) {
                int kg = ks * 32 + quad * 8;
                int tap = kg >> 6, ic = kg & 63;
                s8v b = *(const s8v*)(h2 + cg * H2_AS + (2 * p + tap) * H2_RS + ic);
                acc = MFMA16(a[ks], b, acc);
            }
            if (col < AB) {
                unsigned int lo = f2bu(fmaxf(acc[0] + bia[0], 0.f)) | ((unsigned int)f2bu(fmaxf(acc[1] + bia[1], 0.f)) << 16);
                unsigned int hi = f2bu(fmaxf(acc[2] + bia[2], 0.f)) | ((unsigned int)f2bu(fmaxf(acc[3] + bia[3], 0.f)) << 16);
                *(uint2*)(c3 + col * C3_AS + p * 128 + ocr) = make_uint2(lo, hi);
            }
        }
    }
    __syncthreads();

    // ---- epilogue: mean over 3 p, valid mask, + type_emb (coalesced rows) ----
    if (tid < AB * 16) {
        int ag = tid >> 4;
        int ocg = (tid & 15) * 8;
        long agl = agent0 + ag;
        if (agl < NAG) {
            const short* cb = c3 + ag * C3_AS;
            s8v x0 = *(const s8v*)(cb + ocg);
            s8v x1 = *(const s8v*)(cb + 128 + ocg);
            s8v x2 = *(const s8v*)(cb + 256 + ocg);
            int valid = s_valid[ag];
            int cat = category[agl];
            float vals[8];
#pragma unroll
            for (int j = 0; j < 8; j++) {
                float m = (bu2f((unsigned short)x0[j]) + bu2f((unsigned short)x1[j]) +
                           bu2f((unsigned short)x2[j])) * (1.f / 3.f);
                vals[j] = valid ? m : 0.f;
            }
            if (DT) {
                s8v te = *(const s8v*)((const bf16*)type_emb + (long)cat * 128 + ocg);
                s8v o;
#pragma unroll
                for (int j = 0; j < 8; j++)
                    o[j] = (short)f2bu(vals[j] + bu2f((unsigned short)te[j]));
                *(s8v*)((bf16*)out + agl * 128 + ocg) = o;
            } else {
                const float4* tep = (const float4*)((const float*)type_emb + (long)cat * 128 + ocg);
                float4 t0 = tep[0], t1 = tep[1];
                float4 o0 = make_float4(vals[0] + t0.x, vals[1] + t0.y, vals[2] + t0.z, vals[3] + t0.w);
                float4 o1 = make_float4(vals[4] + t1.x, vals[5] + t1.y, vals[6] + t1.z, vals[7] + t1.w);
                float4* op = (float4*)((float*)out + agl * 128 + ocg);
                op[0] = o0; op[1] = o1;
            }
        }
    }
}

__global__ __launch_bounds__(256) void stage1_kernel(
    const void* __restrict__ pos, const void* __restrict__ heading,
    const void* __restrict__ vel, const void* __restrict__ shp,
    const void* __restrict__ vmask, const int* __restrict__ category,
    const void* __restrict__ type_emb, void* __restrict__ out) {
    __shared__ __align__(16) char smem[SMEM_BYTES];
    long agent0 = (long)blockIdx.x * AB;
    if (g_dtype) stage1_body<1>(pos, heading, vel, shp, vmask, category, type_emb, out, smem, agent0);
    else         stage1_body<0>(pos, heading, vel, shp, vmask, category, type_emb, out, smem, agent0);
}

// ---------------- stage 2 (256 threads): ego cross-attention, overwrites out[b][0] ----------------
// q/k pre-folded (g_wqk, g_qb). softmax weights sum to 1 =>
// o[d] = bv[d] + sum_e y_{h(d)}[e] * Wv[d][e], y_h[e] = sum_s att[h,s]*xe[s,e].
template <int DT>
__device__ __forceinline__ void stage2_body(
    const void* cs, const int* category,
    const void* se_w, const void* se_b, const void* pe,
    const void* ipw, const void* ipb, const void* opw, const void* opb,
    const void* type_emb, void* out, float* sm) {
    const int b = blockIdx.x;
    const int tid = threadIdx.x;
    const int d = tid & 127, half = tid >> 7;

    float* s_xe  = sm;                  // [6][128]
    float* s_y   = s_xe + 768;          // [4][128]
    float* s_sc  = s_y + 512;           // [24] (+pad)
    float* s_att = s_sc + 32;           // [24] (+pad)
    float* s_o   = s_att + 32;          // [128]
    float* s_par = s_o + 128;           // [2][128]

    for (int idx = tid; idx < 768; idx += 256) {
        int s = idx >> 7, dd = idx & 127;
        float ego = ldf<DT>(cs, b * 6 + s);
        s_xe[idx] = fmaf(ego, ldf<DT>(se_w, s * 128 + dd),
                         ldf<DT>(se_b, s * 128 + dd) + ldf<DT>(pe, s * 128 + dd));
    }
    __syncthreads();

    // scores: 24 (h,s) pairs x 4 lanes each, 32-e partials + width-4 reduce
    if (tid < 96) {
        int g = tid >> 2, lig = tid & 3;
        int h = g / 6, s = g - h * 6;
        const float* xr = s_xe + s * 128 + lig * 32;
        const float* wr = g_wqk + h * 128 + lig * 32;
        float t = 0.f;
#pragma unroll
        for (int e = 0; e < 32; e++) t = fmaf(xr[e], wr[e], t);
        t += __shfl_xor(t, 1, 4);
        t += __shfl_xor(t, 2, 4);
        if (lig == 0) s_sc[g] = (t + g_qb[h]) * 0.17677669529663687f;
    }
    __syncthreads();

    if (tid < 4) {
        float mx = -1e30f;
#pragma unroll
        for (int s = 0; s < 6; s++) mx = fmaxf(mx, s_sc[tid * 6 + s]);
        float sum = 0.f, ex[6];
#pragma unroll
        for (int s = 0; s < 6; s++) { ex[s] = expf(s_sc[tid * 6 + s] - mx); sum += ex[s]; }
        float inv = 1.f / sum;
#pragma unroll
        for (int s = 0; s < 6; s++) s_att[tid * 6 + s] = ex[s] * inv;
    }
    __syncthreads();

    for (int idx = tid; idx < 512; idx += 256) {
        int h = idx >> 7, e = idx & 127;
        float y = 0.f;
#pragma unroll
        for (int s = 0; s < 6; s++) y = fmaf(s_att[h * 6 + s], s_xe[s * 128 + e], y);
        s_y[idx] = y;
    }
    __syncthreads();

    {   // o[d] partial over 64 e (Wv row = ipw row 256+d)
        int h = d >> 5;
        const float* yr = s_y + h * 128 + half * 64;
        s_par[half * 128 + d] = rowdot64<DT>(ipw, (long)(256 + d) * 128 + half * 64, yr);
    }
    __syncthreads();
    if (half == 0) s_o[d] = s_par[d] + s_par[128 + d] + ldf<DT>(ipb, 256 + d);
    __syncthreads();

    {   // x_ego[d] partial over 64 e (Wo row d)
        const float* orr = s_o + half * 64;
        s_par[half * 128 + d] = rowdot64<DT>(opw, (long)d * 128 + half * 64, orr);
    }
    __syncthreads();
    if (half == 0) {
        float x = s_par[d] + s_par[128 + d] + ldf<DT>(opb, d);
        int cat = category[(long)b * AAG];
        stf<DT>(out, (long)b * AAG * 128 + d, x + ldf<DT>(type_emb, cat * 128 + d));
    }
}

__global__ __launch_bounds__(256) void stage2_kernel(
    const void* __restrict__ cs, const int* __restrict__ category,
    const void* __restrict__ se_w, const void* __restrict__ se_b,
    const void* __restrict__ pe,
    const void* __restrict__ ipw, const void* __restrict__ ipb,
    const void* __restrict__ opw, const void* __restrict__ opb,
    const void* __restrict__ type_emb, void* __restrict__ out) {
    __shared__ float sm[1728];
    if (g_dtype) stage2_body<1>(cs, category, se_w, se_b, pe, ipw, ipb, opw, opb, type_emb, out, sm);
    else         stage2_body<0>(cs, category, se_w, se_b, pe, ipw, ipb, opw, opb, type_emb, out, sm);
}

extern "C" void kernel_launch(void* const* d_in, const int* in_sizes, int n_in,
                              void* d_out, int out_size, void* d_ws, size_t ws_size,
                              hipStream_t stream) {
    const void* position      = d_in[0];
    const void* heading       = d_in[1];
    const void* velocity      = d_in[2];
    const void* shape         = d_in[3];
    const void* current_state = d_in[4];
    const int*  category      = (const int*)d_in[5];
    const void* valid_mask    = d_in[6];
    const void* conv1_w = d_in[7];
    const void* conv1_b = d_in[8];
    const void* conv2_w = d_in[9];
    const void* conv2_b = d_in[10];
    const void* conv3_w = d_in[11];
    const void* conv3_b = d_in[12];
    const void* se_w    = d_in[13];
    const void* se_b    = d_in[14];
    const void* pos_embed = d_in[15];
    const void* query     = d_in[16];
    const void* in_proj_w = d_in[17];
    const void* in_proj_b = d_in[18];
    const void* out_proj_w = d_in[19];
    const void* out_proj_b = d_in[20];
    const void* type_emb   = d_in[21];

    hipLaunchKernelGGL(prep_kernel, dim3(65), dim3(256), 0, stream,
                       (const unsigned int*)position, (const unsigned char*)valid_mask,
                       conv1_w, conv1_b, conv2_w, conv2_b, conv3_w, conv3_b,
                       query, in_proj_w, in_proj_b);

    hipLaunchKernelGGL(stage1_kernel, dim3(NB1), dim3(256), 0, stream,
                       position, heading, velocity, shape, valid_mask, category,
                       type_emb, d_out);

    hipLaunchKernelGGL(stage2_kernel, dim3(BB), dim3(256), 0, stream,
                       current_state, category, se_w, se_b, pos_embed,
                       in_proj_w, in_proj_b, out_proj_w, out_proj_b, type_emb, d_out);
}

// Round 7
// 296.541 us; speedup vs baseline: 1.2465x; 1.1193x over previous
//
#include <hip/hip_runtime.h>
#include <hip/hip_bf16.h>

// AgentEncoder: B=256, A=512, T=21, DIM=128, SC=6, NHEAD=4, HD=32
// Round 7: persistent-chunk stage1. Round-6 post-mortem: block throughput is
// pinned at ~63 blocks/us across 41%/61% occupancy => per-block cost, not
// wave slots. So: grid 2048, each block runs 4 chunks of 16 agents with the
// round-1 verified phase structure, PLUS:
//  - register prefetch of next chunk's inputs (raw, undecoded) issued after
//    the feature phase => HBM latency hides under conv1-3;
//  - lgkm-only barriers (s_waitcnt lgkmcnt(0) + raw s_barrier, HK/T4 pattern)
//    so prefetch vmcnt survives phase barriers (__syncthreads would drain);
//  - s_valid double-buffer (no init barrier, no read/zero race).
// prep/stage2 unchanged from round 6 (separate slim dispatches).

#define BB 256
#define AAG 512
#define TT 21
#define NAG (BB * AAG)
#define AB 16                  // agents per chunk
#define CHUNKS 4
#define GRID1 (NAG / (AB * CHUNKS))   // 2048

typedef __hip_bfloat16 bf16;
typedef __attribute__((ext_vector_type(8))) short s8v;   // 8 bf16 = 4 VGPR
typedef __attribute__((ext_vector_type(4))) float f4v;   // mfma acc

__device__ int g_dtype;        // 1 = bf16 inputs, 0 = f32 inputs
__device__ int g_mask_mode;    // 0=i32, 1=u8, 2=f32, 3=bf16
__device__ __align__(16) short g_w1p[32 * 64];    // [oc][k=tap*16+ic], pad0
__device__ __align__(16) short g_w2p[64 * 96];    // [oc][k=tap*32+ic]
__device__ __align__(16) short g_w3p[128 * 192];  // [oc][k=tap*64+ic]
__device__ __align__(16) float g_b1[32];
__device__ __align__(16) float g_b2[64];
__device__ __align__(16) float g_b3[128];
__device__ __align__(16) float g_wqk[4 * 128];    // per-head q-folded Wk
__device__ __align__(16) float g_qb[4];           // per-head q.bk

template <int DT>
__device__ __forceinline__ float ldf(const void* p, long i) {
    if (DT) return __bfloat162float(((const bf16*)p)[i]);
    return ((const float*)p)[i];
}
template <int DT>
__device__ __forceinline__ void stf(void* p, long i, float v) {
    if (DT) ((bf16*)p)[i] = __float2bfloat16(v);
    else    ((float*)p)[i] = v;
}
__device__ __forceinline__ unsigned short f2bu(float x) {
    bf16 b = __float2bfloat16(x);
    union { bf16 b; unsigned short u; } cv; cv.b = b; return cv.u;
}
__device__ __forceinline__ float bu2f(unsigned short u) {
    union { unsigned int i; float f; } cv; cv.i = ((unsigned int)u) << 16; return cv.f;
}
__device__ __forceinline__ bool mask_at(const void* p, long i, int mode) {
    if (mode == 0) return ((const int*)p)[i] != 0;
    if (mode == 1) return ((const unsigned char*)p)[i] != 0;
    if (mode == 2) return ((const float*)p)[i] != 0.f;
    return (((const unsigned short*)p)[i] & 0x7fff) != 0;
}

// ---- raw (undecoded) input loads for prefetch: no dependent VALU at issue ----
template <int DT> struct RawV { using T2 = float2; using T1 = float; };
template <> struct RawV<1> { using T2 = unsigned int; using T1 = unsigned short; };

__device__ __forceinline__ float2 dec2v(float2 v) { return v; }
__device__ __forceinline__ float2 dec2v(unsigned int u) {
    return make_float2(bu2f((unsigned short)(u & 0xffffu)), bu2f((unsigned short)(u >> 16)));
}
__device__ __forceinline__ float dec1v(float v) { return v; }
__device__ __forceinline__ float dec1v(unsigned short u) { return bu2f(u); }

template <int DT>
__device__ __forceinline__ typename RawV<DT>::T2 ldr2(const void* p, long i) {
    if constexpr (DT) return *(const unsigned int*)((const bf16*)p + i);
    else return *(const float2*)((const float*)p + i);
}
template <int DT>
__device__ __forceinline__ typename RawV<DT>::T1 ldr1(const void* p, long i) {
    if constexpr (DT) return ((const unsigned short*)p)[i];
    else return ((const float*)p)[i];
}
__device__ __forceinline__ unsigned int mask_raw(const void* p, long i, int mode) {
    if (mode == 0) return ((const unsigned int*)p)[i];
    if (mode == 1) return ((const unsigned char*)p)[i];
    if (mode == 2) return ((const unsigned int*)p)[i];   // f32 raw bits
    return ((const unsigned short*)p)[i];
}
__device__ __forceinline__ bool mask_dec(unsigned int r, int mode) {
    if (mode == 2) return (r & 0x7fffffffu) != 0;        // f32 != 0 (+-0 excluded)
    if (mode == 3) return (r & 0x7fffu) != 0;            // bf16 != 0
    return r != 0;
}

// lgkm-only barrier: orders LDS, leaves global (vmcnt) loads in flight.
__device__ __forceinline__ void bar_lds() {
    asm volatile("s_waitcnt lgkmcnt(0)" ::: "memory");
    __builtin_amdgcn_s_barrier();
}

// 64-element row-dot: sum_i W[off+i] * y[i], vectorized 16B loads
template <int DT>
__device__ __forceinline__ float rowdot64(const void* W, long off, const float* y) {
    float acc = 0.f;
    if (DT) {
        const unsigned short* wr = (const unsigned short*)W + off;
#pragma unroll
        for (int i = 0; i < 8; i++) {
            uint4 w = *(const uint4*)(wr + i * 8);
            acc = fmaf(bu2f((unsigned short)(w.x & 0xffffu)), y[i * 8 + 0], acc);
            acc = fmaf(bu2f((unsigned short)(w.x >> 16)),     y[i * 8 + 1], acc);
            acc = fmaf(bu2f((unsigned short)(w.y & 0xffffu)), y[i * 8 + 2], acc);
            acc = fmaf(bu2f((unsigned short)(w.y >> 16)),     y[i * 8 + 3], acc);
            acc = fmaf(bu2f((unsigned short)(w.z & 0xffffu)), y[i * 8 + 4], acc);
            acc = fmaf(bu2f((unsigned short)(w.z >> 16)),     y[i * 8 + 5], acc);
            acc = fmaf(bu2f((unsigned short)(w.w & 0xffffu)), y[i * 8 + 6], acc);
            acc = fmaf(bu2f((unsigned short)(w.w >> 16)),     y[i * 8 + 7], acc);
        }
    } else {
        const float* wr = (const float*)W + off;
#pragma unroll
        for (int i = 0; i < 16; i++) {
            float4 w = *(const float4*)(wr + i * 4);
            acc = fmaf(w.x, y[i * 4 + 0], acc);
            acc = fmaf(w.y, y[i * 4 + 1], acc);
            acc = fmaf(w.z, y[i * 4 + 2], acc);
            acc = fmaf(w.w, y[i * 4 + 3], acc);
        }
    }
    return acc;
}

// ---------------- weight pad/transpose/cast (grid-stride over 64 blocks) ----------------
template <int DT>
__device__ __forceinline__ void prep_body(const void* w1, const void* b1,
                                          const void* w2, const void* b2,
                                          const void* w3, const void* b3) {
    int tid = blockIdx.x * 256 + threadIdx.x;
    const int nt = 64 * 256;
    for (int i = tid; i < 32 * 64; i += nt) {
        int oc = i >> 6, k = i & 63, tap = k >> 4, ic = k & 15;
        float v = (tap < 3 && ic < 9) ? ldf<DT>(w1, oc * 27 + ic * 3 + tap) : 0.f;
        g_w1p[i] = (short)f2bu(v);
    }
    for (int i = tid; i < 64 * 96; i += nt) {
        int oc = i / 96, k = i % 96, tap = k >> 5, ic = k & 31;
        g_w2p[i] = (short)f2bu(ldf<DT>(w2, oc * 96 + ic * 3 + tap));
    }
    for (int i = tid; i < 128 * 192; i += nt) {
        int oc = i / 192, k = i % 192, tap = k >> 6, ic = k & 63;
        g_w3p[i] = (short)f2bu(ldf<DT>(w3, oc * 192 + ic * 3 + tap));
    }
    for (int i = tid; i < 32; i += nt) g_b1[i] = ldf<DT>(b1, i);
    for (int i = tid; i < 64; i += nt) g_b2[i] = ldf<DT>(b2, i);
    for (int i = tid; i < 128; i += nt) g_b3[i] = ldf<DT>(b3, i);
}

// block 64: q = query@Wq^T+bq, then fold through Wk: g_wqk[h][e], g_qb[h]
template <int DT>
__device__ __forceinline__ void qprep_body(const void* query, const void* ipw,
                                           const void* ipb, float* sq) {
    int tid = threadIdx.x;
    if (tid < 128) {
        float acc = ldf<DT>(ipb, tid);
        for (int e = 0; e < 128; e++)
            acc = fmaf(ldf<DT>(query, e), ldf<DT>(ipw, (long)tid * 128 + e), acc);
        sq[tid] = acc;
    }
    __syncthreads();
    int e = tid & 127, hb = tid >> 7;
    for (int h = hb; h < 4; h += 2) {
        float acc = 0.f;
#pragma unroll
        for (int j = 0; j < 32; j++)
            acc = fmaf(sq[h * 32 + j], ldf<DT>(ipw, (long)(128 + h * 32 + j) * 128 + e), acc);
        g_wqk[h * 128 + e] = acc;
    }
    if (tid < 4) {
        float acc = 0.f;
#pragma unroll
        for (int j = 0; j < 32; j++)
            acc = fmaf(sq[tid * 32 + j], ldf<DT>(ipb, 128 + tid * 32 + j), acc);
        g_qb[tid] = acc;
    }
}

// ---------------- launch A: per-block detect + prep + q-fold ----------------
__global__ __launch_bounds__(256) void prep_kernel(
    const unsigned int* __restrict__ pw, const unsigned char* __restrict__ m,
    const void* __restrict__ w1, const void* __restrict__ b1,
    const void* __restrict__ w2, const void* __restrict__ b2,
    const void* __restrict__ w3, const void* __restrict__ b3,
    const void* __restrict__ query, const void* __restrict__ ipw,
    const void* __restrict__ ipb) {
    __shared__ int cls[4];
    __shared__ int mv;
    __shared__ int good;
    __shared__ float sq[128];
    int tid = threadIdx.x;
    if (tid < 4) cls[tid] = 0;
    if (tid == 0) { mv = 0; good = 0; }
    __syncthreads();
    int g = 0;
    for (int i = tid; i < 1024; i += 256) {
        unsigned int w = pw[i];
        unsigned int h0 = w & 0xffffu, h1 = w >> 16;
        unsigned int e0 = (h0 >> 7) & 0xff, e1 = (h1 >> 7) & 0xff;
        if (h0 == 0 || (e0 >= 90 && e0 <= 160)) g++;
        if (h1 == 0 || (e1 >= 90 && e1 <= 160)) g++;
    }
    atomicAdd(&good, g);
    int l0 = 0, l1 = 0, l2 = 0, l3 = 0, lm = 0;
    for (int i = tid; i < 4096; i += 256) {
        int v = m[i];
        if (v) {
            switch (i & 3) { case 0: l0 = 1; break; case 1: l1 = 1; break;
                             case 2: l2 = 1; break; default: l3 = 1; }
            if (v > lm) lm = v;
        }
    }
    if (l0) atomicOr(&cls[0], 1);
    if (l1) atomicOr(&cls[1], 1);
    if (l2) atomicOr(&cls[2], 1);
    if (l3) atomicOr(&cls[3], 1);
    atomicMax(&mv, lm);
    __syncthreads();
    int dt = (good >= 1740) ? 1 : 0;
    int mode;
    if (!cls[1] && !cls[2] && !cls[3]) mode = 0;
    else if (!cls[0] && !cls[1])       mode = 2;
    else if (mv <= 1)                  mode = 1;
    else                               mode = 3;
    if (blockIdx.x == 0 && tid == 0) { g_dtype = dt; g_mask_mode = mode; }

    if (blockIdx.x < 64) {
        if (dt) prep_body<1>(w1, b1, w2, b2, w3, b3);
        else    prep_body<0>(w1, b1, w2, b2, w3, b3);
    } else {
        if (dt) qprep_body<1>(query, ipw, ipb, sq);
        else    qprep_body<0>(query, ipw, ipb, sq);
    }
}

// ---------------- stage 1: 2048 persistent blocks x 4 chunks x 16 agents ----------------
// LDS (shorts). Region A: feat [16][FEAT_AS], reused as h2. Region B: h1
// [16][H1_AS], reused as c3. Round-1 measured strides (bank behavior kept).
#define FEAT_RS 24     // rows t=0..21 (20/21 zero); 48 B
#define FEAT_AS 568    // 1136 B == -4 banks (mod 32)
#define H1_RS 40       // rows t=0..10 (10 zero); 80 B
#define H1_AS 440      // 880 B == -4 banks
#define H2_RS 72       // rows r=0..6 (0,6 zero); 144 B
#define H2_AS 504      // 1008 B == -4 banks
#define C3_AS 392      // 3*128 + 8 pad; 784 B == +4 banks
#define OFF_H1 9088    // shorts = 16*FEAT_AS
#define OFF_VALID 32256 // bytes; s_valid[2][16] ints = 128 B
#define SMEM_BYTES 32384 // -> 32768 alloc => 5 blocks/CU

#define MFMA16(a, b, c) __builtin_amdgcn_mfma_f32_16x16x32_bf16((a), (b), (c), 0, 0, 0)

template <int DT>
__device__ __forceinline__ void emit_row(
    short* feat, int* vcur, int ag, int t, int mode,
    unsigned int m0r, unsigned int m1r,
    typename RawV<DT>::T2 par, typename RawV<DT>::T2 pbr,
    typename RawV<DT>::T2 var, typename RawV<DT>::T2 vbr,
    typename RawV<DT>::T1 h0r, typename RawV<DT>::T1 h1r,
    typename RawV<DT>::T2 svr) {
    bool vmt = mask_dec(m0r, mode);
    bool m2 = vmt && mask_dec(m1r, mode);
    if (vmt) atomicOr(&vcur[ag], 1);
    float2 pa = dec2v(par), pb = dec2v(pbr), va = dec2v(var), vb = dec2v(vbr);
    float hh0 = dec1v(h0r), hh1 = dec1v(h1r);
    float2 sv = dec2v(svr);
    float dh = m2 ? (hh1 - hh0) : 0.f;          // masked: cos=1, sin=0 (ref)
    float sn, cn;
    __sincosf(dh, &sn, &cn);
    unsigned int p0 = f2bu(m2 ? pb.x - pa.x : 0.f) | ((unsigned int)f2bu(m2 ? pb.y - pa.y : 0.f) << 16);
    unsigned int p1 = f2bu(m2 ? vb.x - va.x : 0.f) | ((unsigned int)f2bu(m2 ? vb.y - va.y : 0.f) << 16);
    unsigned int p2 = f2bu(cn) | ((unsigned int)f2bu(sn) << 16);
    unsigned int p3 = f2bu(sv.x) | ((unsigned int)f2bu(sv.y) << 16);
    unsigned int p4 = (unsigned int)f2bu(m2 ? 1.f : 0.f);
    short* row = feat + ag * FEAT_AS + t * FEAT_RS;
    *(uint4*)row = make_uint4(p0, p1, p2, p3);
    *(uint4*)(row + 8) = make_uint4(p4, 0, 0, 0);
}

template <int DT>
__device__ __forceinline__ void stage1_body(
    const void* pos, const void* heading, const void* vel, const void* shp,
    const void* vmask, const int* category, const void* type_emb, void* out,
    char* smem) {
    short* feat = (short*)smem;               // region A
    short* h1   = (short*)smem + OFF_H1;      // region B
    short* h2   = (short*)smem;               // region A reuse (feat dead after conv1)
    short* c3   = (short*)smem + OFF_H1;      // region B reuse (h1 dead after conv2)
    int* s_valid = (int*)(smem + OFF_VALID);  // [2][16] double-buffered

    const int tid = threadIdx.x;
    const int wave = tid >> 6, lane = tid & 63;
    const int col = lane & 15, quad = lane >> 4;
    const int mode = g_mask_mode;
    const long agent0_blk = (long)blockIdx.x * (AB * CHUNKS);

    // row ownership: row1 = tid (ag=tid/20, t=tid%20, 256 rows);
    // row2 = 256+tid for tid<64; zero rows t=20/21 by tid in [96,128).
    const int ag1 = tid / 20, t1 = tid % 20;
    const int ag2 = (256 + tid) / 20, t2 = (256 + tid) % 20;   // valid for tid<64
    const bool zrow = (tid >= 96 && tid < 128);
    const int zi = tid - 96, zag = zi >> 1;
    const bool zth = zrow && !(zi & 1);                        // t=20 mask thread

    // prefetch registers (raw, undecoded)
    typename RawV<DT>::T2 pa1{}, pb1{}, va1{}, vb1{}, pa2{}, pb2{}, va2{}, vb2{};
    typename RawV<DT>::T1 h01{}, h11{};
    unsigned int m01 = 0, m11 = 0, m02 = 0, m12 = 0, mz = 0;

    auto prefetch = [&](int c) {
        long a0c = agent0_blk + (long)c * AB;
        {
            long base = (a0c + ag1) * TT + t1;
            m01 = mask_raw(vmask, base, mode);
            m11 = mask_raw(vmask, base + 1, mode);
            pa1 = ldr2<DT>(pos, base * 2); pb1 = ldr2<DT>(pos, base * 2 + 2);
            va1 = ldr2<DT>(vel, base * 2); vb1 = ldr2<DT>(vel, base * 2 + 2);
            h01 = ldr1<DT>(heading, base); h11 = ldr1<DT>(heading, base + 1);
        }
        if (tid < 64) {
            long base = (a0c + ag2) * TT + t2;
            m02 = mask_raw(vmask, base, mode);
            m12 = mask_raw(vmask, base + 1, mode);
            pa2 = ldr2<DT>(pos, base * 2); pb2 = ldr2<DT>(pos, base * 2 + 2);
            va2 = ldr2<DT>(vel, base * 2); vb2 = ldr2<DT>(vel, base * 2 + 2);
        }
        if (zth) mz = mask_raw(vmask, (a0c + zag) * TT + 20, mode);
    };

    // prologue: zero both valid buffers, prefetch chunk 0
    if (tid < 32) s_valid[tid] = 0;
    prefetch(0);
    bar_lds();

    for (int c = 0; c < CHUNKS; ++c) {
        int* vcur = s_valid + (c & 1) * 16;
        long a0c = agent0_blk + (long)c * AB;

        // ---- feature phase: decode prefetched regs -> feat; shape/row2-heading direct ----
        {
            auto sv1r = ldr2<DT>(shp, ((a0c + ag1) * TT + t1) * 2 + 2);
            typename RawV<DT>::T2 sv2r{};
            typename RawV<DT>::T1 h02{}, h12{};
            if (tid < 64) {
                long base2 = (a0c + ag2) * TT + t2;
                sv2r = ldr2<DT>(shp, base2 * 2 + 2);
                h02 = ldr1<DT>(heading, base2);
                h12 = ldr1<DT>(heading, base2 + 1);
            }
            ((unsigned int*)h1)[(tid >> 4) * 220 + 200 + (tid & 15)] = 0;  // h1 row 10
            if (zrow) {                                   // feat rows t=20,21 zero
                short* row = feat + zag * FEAT_AS + (20 + (zi & 1)) * FEAT_RS;
                *(uint4*)row = make_uint4(0, 0, 0, 0);
                *(uint4*)(row + 8) = make_uint4(0, 0, 0, 0);
                if (zth && mask_dec(mz, mode)) atomicOr(&vcur[zag], 1);
            }
            emit_row<DT>(feat, vcur, ag1, t1, mode, m01, m11, pa1, pb1, va1, vb1, h01, h11, sv1r);
            if (tid < 64)
                emit_row<DT>(feat, vcur, ag2, t2, mode, m02, m12, pa2, pb2, va2, vb2, h02, h12, sv2r);
        }
        if (c + 1 < CHUNKS) prefetch(c + 1);   // issue next chunk's loads now
        bar_lds();

        // ---- conv1: M=32 (2 Mt), K=64, N=16ag x 10p => ag=col ----
        {
            int Mt = wave >> 1;
            int oc = Mt * 16 + col;
            s8v a0 = *(const s8v*)(g_w1p + oc * 64 + quad * 8);
            s8v a1 = *(const s8v*)(g_w1p + oc * 64 + 32 + quad * 8);
            int k0 = quad * 8, k1 = 32 + quad * 8;
            int tap0 = k0 >> 4, ic0 = k0 & 15;
            int tap1 = k1 >> 4, ic1 = k1 & 15;
            int ocr = Mt * 16 + quad * 4;
            f4v bia = *(const f4v*)(g_b1 + ocr);
            const short* agbase = feat + col * FEAT_AS;
#pragma unroll
            for (int i = 0; i < 5; i++) {
                int p = (wave & 1) * 5 + i;
                const short* bb = agbase + 2 * p * FEAT_RS;
                s8v b0 = *(const s8v*)(bb + tap0 * FEAT_RS + ic0);
                s8v b1 = *(const s8v*)(bb + tap1 * FEAT_RS + ic1);
                f4v acc = {0.f, 0.f, 0.f, 0.f};
                acc = MFMA16(a0, b0, acc);
                acc = MFMA16(a1, b1, acc);
                unsigned int lo = f2bu(fmaxf(acc[0] + bia[0], 0.f)) | ((unsigned int)f2bu(fmaxf(acc[1] + bia[1], 0.f)) << 16);
                unsigned int hi = f2bu(fmaxf(acc[2] + bia[2], 0.f)) | ((unsigned int)f2bu(fmaxf(acc[3] + bia[3], 0.f)) << 16);
                *(uint2*)(h1 + col * H1_AS + p * H1_RS + ocr) = make_uint2(lo, hi);
            }
        }
        bar_lds();

        // ---- conv2: M=64 (4 Mt), K=96, N=16ag x 5p; zero h2 pad rows 0 & 6 ----
        {
            unsigned int* h2u = (unsigned int*)h2;
            for (int i = tid; i < 1024; i += 256) {
                int a2 = i >> 6, r = (i >> 5) & 1, cc = i & 31;
                h2u[a2 * 252 + r * 216 + cc] = 0;
            }
            int Mt = wave;
            int oc = Mt * 16 + col;
            s8v a[3];
#pragma unroll
            for (int ks = 0; ks < 3; ks++)
                a[ks] = *(const s8v*)(g_w2p + oc * 96 + ks * 32 + quad * 8);
            int ocr = Mt * 16 + quad * 4;
            f4v bia = *(const f4v*)(g_b2 + ocr);
#pragma unroll
            for (int p = 0; p < 5; p++) {
                f4v acc = {0.f, 0.f, 0.f, 0.f};
#pragma unroll
                for (int ks = 0; ks < 3; ks++) {
                    s8v b = *(const s8v*)(h1 + col * H1_AS + (2 * p + ks) * H1_RS + quad * 8);
                    acc = MFMA16(a[ks], b, acc);
                }
                unsigned int lo = f2bu(fmaxf(acc[0] + bia[0], 0.f)) | ((unsigned int)f2bu(fmaxf(acc[1] + bia[1], 0.f)) << 16);
                unsigned int hi = f2bu(fmaxf(acc[2] + bia[2], 0.f)) | ((unsigned int)f2bu(fmaxf(acc[3] + bia[3], 0.f)) << 16);
                *(uint2*)(h2 + col * H2_AS + (p + 1) * H2_RS + ocr) = make_uint2(lo, hi);
            }
        }
        bar_lds();

        // ---- conv3: M=128 (8 Mt, 2/wave), K=192 (6 slices), N=16ag x 3p ----
#pragma unroll
        for (int m2 = 0; m2 < 2; m2++) {
            int Mt = wave * 2 + m2;
            int oc = Mt * 16 + col;
            s8v a[6];
#pragma unroll
            for (int ks = 0; ks < 6; ks++)
                a[ks] = *(const s8v*)(g_w3p + oc * 192 + ks * 32 + quad * 8);
            int ocr = Mt * 16 + quad * 4;
            f4v bia = *(const f4v*)(g_b3 + ocr);
#pragma unroll
            for (int p = 0; p < 3; p++) {
                f4v acc = {0.f, 0.f, 0.f, 0.f};
#pragma unroll
                for (int ks = 0; ks < 6; ks++) {
                    int kg = ks * 32 + quad * 8;
                    int tap = kg >> 6, ic = kg & 63;
                    s8v b = *(const s8v*)(h2 + col * H2_AS + (2 * p + tap) * H2_RS + ic);
                    acc = MFMA16(a[ks], b, acc);
                }
                unsigned int lo = f2bu(fmaxf(acc[0] + bia[0], 0.f)) | ((unsigned int)f2bu(fmaxf(acc[1] + bia[1], 0.f)) << 16);
                unsigned int hi = f2bu(fmaxf(acc[2] + bia[2], 0.f)) | ((unsigned int)f2bu(fmaxf(acc[3] + bia[3], 0.f)) << 16);
                *(uint2*)(c3 + col * C3_AS + p * 128 + ocr) = make_uint2(lo, hi);
            }
        }
        bar_lds();

        // ---- epilogue: mean over 3 p, valid mask, + type_emb (coalesced rows) ----
        {
            int ag = tid >> 4;
            int ocg = (tid & 15) * 8;
            long agl = a0c + ag;
            const short* cb = c3 + ag * C3_AS;
            s8v x0 = *(const s8v*)(cb + ocg);
            s8v x1 = *(const s8v*)(cb + 128 + ocg);
            s8v x2 = *(const s8v*)(cb + 256 + ocg);
            int valid = vcur[ag];
            int cat = category[agl];
            float vals[8];
#pragma unroll
            for (int j = 0; j < 8; j++) {
                float m = (bu2f((unsigned short)x0[j]) + bu2f((unsigned short)x1[j]) +
                           bu2f((unsigned short)x2[j])) * (1.f / 3.f);
                vals[j] = valid ? m : 0.f;
            }
            if (DT) {
                s8v te = *(const s8v*)((const bf16*)type_emb + (long)cat * 128 + ocg);
                s8v o;
#pragma unroll
                for (int j = 0; j < 8; j++)
                    o[j] = (short)f2bu(vals[j] + bu2f((unsigned short)te[j]));
                *(s8v*)((bf16*)out + agl * 128 + ocg) = o;
            } else {
                const float4* tep = (const float4*)((const float*)type_emb + (long)cat * 128 + ocg);
                float4 t0 = tep[0], t1 = tep[1];
                float4 o0 = make_float4(vals[0] + t0.x, vals[1] + t0.y, vals[2] + t0.z, vals[3] + t0.w);
                float4 o1 = make_float4(vals[4] + t1.x, vals[5] + t1.y, vals[6] + t1.z, vals[7] + t1.w);
                float4* op = (float4*)((float*)out + agl * 128 + ocg);
                op[0] = o0; op[1] = o1;
            }
        }
        if (tid < 16) s_valid[((c + 1) & 1) * 16 + tid] = 0;  // re-arm other buffer
        if (c + 1 < CHUNKS) bar_lds();    // WAR: region A/B reuse by next chunk
    }
}

__global__ __launch_bounds__(256) void stage1_kernel(
    const void* __restrict__ pos, const void* __restrict__ heading,
    const void* __restrict__ vel, const void* __restrict__ shp,
    const void* __restrict__ vmask, const int* __restrict__ category,
    const void* __restrict__ type_emb, void* __restrict__ out) {
    __shared__ __align__(16) char smem[SMEM_BYTES];
    if (g_dtype) stage1_body<1>(pos, heading, vel, shp, vmask, category, type_emb, out, smem);
    else         stage1_body<0>(pos, heading, vel, shp, vmask, category, type_emb, out, smem);
}

// ---------------- stage 2 (256 threads): ego cross-attention, overwrites out[b][0] ----------------
template <int DT>
__device__ __forceinline__ void stage2_body(
    const void* cs, const int* category,
    const void* se_w, const void* se_b, const void* pe,
    const void* ipw, const void* ipb, const void* opw, const void* opb,
    const void* type_emb, void* out, float* sm) {
    const int b = blockIdx.x;
    const int tid = threadIdx.x;
    const int d = tid & 127, half = tid >> 7;

    float* s_xe  = sm;                  // [6][128]
    float* s_y   = s_xe + 768;          // [4][128]
    float* s_sc  = s_y + 512;           // [24] (+pad)
    float* s_att = s_sc + 32;           // [24] (+pad)
    float* s_o   = s_att + 32;          // [128]
    float* s_par = s_o + 128;           // [2][128]

    for (int idx = tid; idx < 768; idx += 256) {
        int s = idx >> 7, dd = idx & 127;
        float ego = ldf<DT>(cs, b * 6 + s);
        s_xe[idx] = fmaf(ego, ldf<DT>(se_w, s * 128 + dd),
                         ldf<DT>(se_b, s * 128 + dd) + ldf<DT>(pe, s * 128 + dd));
    }
    __syncthreads();

    if (tid < 96) {
        int g = tid >> 2, lig = tid & 3;
        int h = g / 6, s = g - h * 6;
        const float* xr = s_xe + s * 128 + lig * 32;
        const float* wr = g_wqk + h * 128 + lig * 32;
        float t = 0.f;
#pragma unroll
        for (int e = 0; e < 32; e++) t = fmaf(xr[e], wr[e], t);
        t += __shfl_xor(t, 1, 4);
        t += __shfl_xor(t, 2, 4);
        if (lig == 0) s_sc[g] = (t + g_qb[h]) * 0.17677669529663687f;
    }
    __syncthreads();

    if (tid < 4) {
        float mx = -1e30f;
#pragma unroll
        for (int s = 0; s < 6; s++) mx = fmaxf(mx, s_sc[tid * 6 + s]);
        float sum = 0.f, ex[6];
#pragma unroll
        for (int s = 0; s < 6; s++) { ex[s] = expf(s_sc[tid * 6 + s] - mx); sum += ex[s]; }
        float inv = 1.f / sum;
#pragma unroll
        for (int s = 0; s < 6; s++) s_att[tid * 6 + s] = ex[s] * inv;
    }
    __syncthreads();

    for (int idx = tid; idx < 512; idx += 256) {
        int h = idx >> 7, e = idx & 127;
        float y = 0.f;
#pragma unroll
        for (int s = 0; s < 6; s++) y = fmaf(s_att[h * 6 + s], s_xe[s * 128 + e], y);
        s_y[idx] = y;
    }
    __syncthreads();

    {
        int h = d >> 5;
        const float* yr = s_y + h * 128 + half * 64;
        s_par[half * 128 + d] = rowdot64<DT>(ipw, (long)(256 + d) * 128 + half * 64, yr);
    }
    __syncthreads();
    if (half == 0) s_o[d] = s_par[d] + s_par[128 + d] + ldf<DT>(ipb, 256 + d);
    __syncthreads();

    {
        const float* orr = s_o + half * 64;
        s_par[half * 128 + d] = rowdot64<DT>(opw, (long)d * 128 + half * 64, orr);
    }
    __syncthreads();
    if (half == 0) {
        float x = s_par[d] + s_par[128 + d] + ldf<DT>(opb, d);
        int cat = category[(long)b * AAG];
        stf<DT>(out, (long)b * AAG * 128 + d, x + ldf<DT>(type_emb, cat * 128 + d));
    }
}

__global__ __launch_bounds__(256) void stage2_kernel(
    const void* __restrict__ cs, const int* __restrict__ category,
    const void* __restrict__ se_w, const void* __restrict__ se_b,
    const void* __restrict__ pe,
    const void* __restrict__ ipw, const void* __restrict__ ipb,
    const void* __restrict__ opw, const void* __restrict__ opb,
    const void* __restrict__ type_emb, void* __restrict__ out) {
    __shared__ float sm[1728];
    if (g_dtype) stage2_body<1>(cs, category, se_w, se_b, pe, ipw, ipb, opw, opb, type_emb, out, sm);
    else         stage2_body<0>(cs, category, se_w, se_b, pe, ipw, ipb, opw, opb, type_emb, out, sm);
}

extern "C" void kernel_launch(void* const* d_in, const int* in_sizes, int n_in,
                              void* d_out, int out_size, void* d_ws, size_t ws_size,
                              hipStream_t stream) {
    const void* position      = d_in[0];
    const void* heading       = d_in[1];
    const void* velocity      = d_in[2];
    const void* shape         = d_in[3];
    const void* current_state = d_in[4];
    const int*  category      = (const int*)d_in[5];
    const void* valid_mask    = d_in[6];
    const void* conv1_w = d_in[7];
    const void* conv1_b = d_in[8];
    const void* conv2_w = d_in[9];
    const void* conv2_b = d_in[10];
    const void* conv3_w = d_in[11];
    const void* conv3_b = d_in[12];
    const void* se_w    = d_in[13];
    const void* se_b    = d_in[14];
    const void* pos_embed = d_in[15];
    const void* query     = d_in[16];
    const void* in_proj_w = d_in[17];
    const void* in_proj_b = d_in[18];
    const void* out_proj_w = d_in[19];
    const void* out_proj_b = d_in[20];
    const void* type_emb   = d_in[21];

    hipLaunchKernelGGL(prep_kernel, dim3(65), dim3(256), 0, stream,
                       (const unsigned int*)position, (const unsigned char*)valid_mask,
                       conv1_w, conv1_b, conv2_w, conv2_b, conv3_w, conv3_b,
                       query, in_proj_w, in_proj_b);

    hipLaunchKernelGGL(stage1_kernel, dim3(GRID1), dim3(256), 0, stream,
                       position, heading, velocity, shape, valid_mask, category,
                       type_emb, d_out);

    hipLaunchKernelGGL(stage2_kernel, dim3(BB), dim3(256), 0, stream,
                       current_state, category, se_w, se_b, pos_embed,
                       in_proj_w, in_proj_b, out_proj_w, out_proj_b, type_emb, d_out);
}